// Round 7
// baseline (174.541 us; speedup 1.0000x reference)
//
#include <hip/hip_runtime.h>

// Problem constants (from reference setup_inputs)
constexpr int B  = 32;
constexpr int H  = 256;
constexpr int W  = 1216;
constexpr int HW = H * W;            // 311296
constexpr int N  = B * HW;           // 9961472 elements in gt / weight_map
constexpr int NCHUNK  = N / 4;       // 2490368 float4 chunks = 19 * 2^17
constexpr int BLOCKSZ = 256;
constexpr int GRID    = 1024;        // 4 blocks/CU, 16 waves/CU
constexpr int CSTRIDE = GRID * BLOCKSZ;   // 262144; NCHUNK = 9.5 * CSTRIDE
constexpr int NSLOT   = 16;

// R12 design. R6 post-mortem: time invariant to HBM-vs-cache residency,
// VALU 19%, occupancy 31% — nothing saturated; latency/supply-bound.
// Little's law says effective in-flight is ~1 KB/wave despite VGPR=60
// holding the depth-3 buffers. Root cause: the rotated loop reloads are
// CONDITIONAL (if next<NCHUNK), so the number of outstanding vmem ops at
// the next use is branch-dependent and the waitcnt pass must conservatively
// drain every iteration -> effective depth 1 -> the 47us floor seen in
// every round using this structure (R0, R6).
// Fix: static waitcnt-determinable code. NCHUNK = 19*2^17, so blocks 0..511
// process exactly 10 chunks/thread and blocks 512..1023 exactly 9, each as
// a FULLY-UNROLLED straight-line depth-4 rotation with unconditional loads
// (all guards compile-time). Straight-line code is where LLVM's waitcnt
// pass emits precise counted waits (m97). No inline asm (R9/R10 lesson),
// no nt (R6: cache-warm inputs).

typedef float vfloat4 __attribute__((ext_vector_type(4)));
typedef int   vint4   __attribute__((ext_vector_type(4)));

__device__ __forceinline__ void load3(const float* __restrict__ pred,
                                      const float* __restrict__ gt,
                                      const int*   __restrict__ wm,
                                      int c, vfloat4& p, vfloat4& g, vint4& w)
{
    const int i0 = c * 4;            // flat element index
    const int b  = i0 / HW;          // batch (magic-mul by compiler)
    p = *(const vfloat4*)(pred + (i0 + b * HW));
    g = *(const vfloat4*)(gt + i0);
    w = *(const vint4*)(wm + i0);
}

__device__ __forceinline__ void accum(const vfloat4& p, const vfloat4& g,
                                      const vint4& w, float* sum, int* cnt)
{
    const float e0 = p.x - g.x, e1 = p.y - g.y;
    const float e2 = p.z - g.z, e3 = p.w - g.w;
    const float s0 = e0 * e0, s1 = e1 * e1, s2 = e2 * e2, s3 = e3 * e3;
#pragma unroll
    for (int j = 0; j < 8; ++j) {
        const int bin = j + 1;
        sum[j] += (w.x == bin) ? s0 : 0.f;
        cnt[j] += (w.x == bin) ? 1 : 0;
        sum[j] += (w.y == bin) ? s1 : 0.f;
        cnt[j] += (w.y == bin) ? 1 : 0;
        sum[j] += (w.z == bin) ? s2 : 0.f;
        cnt[j] += (w.z == bin) ? 1 : 0;
        sum[j] += (w.w == bin) ? s3 : 0.f;
        cnt[j] += (w.w == bin) ? 1 : 0;
    }
}

// Fully-unrolled depth-D rotated stream over NIT chunks. Every load is
// unconditional in straight-line code (k+D<NIT is a compile-time guard),
// so the outstanding-vmem count at every accum is statically known and the
// waitcnt pass can emit counted waits instead of drains. All array indices
// become constants after unroll (no scratch, rule #20).
template<int NIT>
__device__ __forceinline__ void stream_chunks(const float* __restrict__ pred,
                                              const float* __restrict__ gt,
                                              const int*   __restrict__ wm,
                                              int start, float* sum, int* cnt)
{
    constexpr int D = (NIT < 4) ? NIT : 4;   // pipeline depth (12 loads out)
    vfloat4 p[D], g[D];
    vint4   w[D];
#pragma unroll
    for (int d = 0; d < D; ++d)
        load3(pred, gt, wm, start + d * CSTRIDE, p[d], g[d], w[d]);
#pragma unroll
    for (int k = 0; k < NIT; ++k) {
        const int s = k % D;
        accum(p[s], g[s], w[s], sum, cnt);
        if (k + D < NIT)   // compile-time after unroll
            load3(pred, gt, wm, start + (k + D) * CSTRIDE, p[s], g[s], w[s]);
    }
}

__global__ __launch_bounds__(BLOCKSZ, 4) void seg_mse_kernel(
    const float* __restrict__ pred,
    const float* __restrict__ gt,
    const int*   __restrict__ wm,
    float* __restrict__ part)
{
    float sum[8] = {0.f, 0.f, 0.f, 0.f, 0.f, 0.f, 0.f, 0.f};
    int   cnt[8] = {0, 0, 0, 0, 0, 0, 0, 0};

    const int start = blockIdx.x * BLOCKSZ + threadIdx.x;

    // Coverage: low blocks own chunks {c : c mod CSTRIDE < CSTRIDE/2} for
    // k=0..9 (start+9*CSTRIDE < 9.5*CSTRIDE = NCHUNK exactly); high blocks
    // own the other half for k=0..8. Disjoint, complete:
    // 131072*10 + 131072*9 = 131072*19 = NCHUNK.
    if (blockIdx.x < GRID / 2)
        stream_chunks<10>(pred, gt, wm, start, sum, cnt);
    else
        stream_chunks<9>(pred, gt, wm, start, sum, cnt);

    // wave (64-lane) butterfly reduction of all 16 partials
    float fcnt[8];
#pragma unroll
    for (int j = 0; j < 8; ++j) fcnt[j] = (float)cnt[j];
#pragma unroll
    for (int j = 0; j < 8; ++j) {
#pragma unroll
        for (int off = 32; off > 0; off >>= 1) {
            sum[j]  += __shfl_down(sum[j], off);
            fcnt[j] += __shfl_down(fcnt[j], off);
        }
    }

    // cross-wave reduction in LDS (256 threads = 4 waves)
    __shared__ float lsum[4][8];
    __shared__ float lcnt[4][8];
    const int wave = threadIdx.x >> 6;
    const int lane = threadIdx.x & 63;
    if (lane == 0) {
#pragma unroll
        for (int j = 0; j < 8; ++j) {
            lsum[wave][j] = sum[j];
            lcnt[wave][j] = fcnt[j];
        }
    }
    __syncthreads();

    // 16 plain coalesced stores per block (one 64B segment)
    if (threadIdx.x < 8) {
        const int j = threadIdx.x;
        part[blockIdx.x * NSLOT + j] =
            lsum[0][j] + lsum[1][j] + lsum[2][j] + lsum[3][j];
    } else if (threadIdx.x < 16) {
        const int j = threadIdx.x - 8;
        part[blockIdx.x * NSLOT + 8 + j] =
            lcnt[0][j] + lcnt[1][j] + lcnt[2][j] + lcnt[3][j];
    }
}

// Single-block reduction of GRID x 16 partials (64 KB, L2-resident).
__global__ __launch_bounds__(1024) void finalize_kernel(
    const float* __restrict__ part,
    float* __restrict__ out)
{
    const int tid = threadIdx.x;
    const int j   = tid & 15;        // slot
    const int g   = tid >> 4;        // group 0..63
    float v = 0.f;
#pragma unroll
    for (int i = 0; i < GRID / 64; ++i) {
        v += part[(g + 64 * i) * NSLOT + j];
    }
    // combine groups within the wave: lanes differing in bits 4,5 share slot j
    v += __shfl_xor(v, 16);
    v += __shfl_xor(v, 32);

    // cross-wave: 16 waves each contribute one value per slot
    __shared__ float wsum[16][16];
    const int wave = tid >> 6;
    const int lane = tid & 63;
    if (lane < 16) wsum[wave][lane] = v;
    __syncthreads();

    __shared__ float fin[16];
    if (tid < 16) {
        float t = 0.f;
#pragma unroll
        for (int w = 0; w < 16; ++w) t += wsum[w][tid];
        fin[tid] = t;
    }
    __syncthreads();

    if (tid == 0) {
        float total = 0.f;
#pragma unroll
        for (int j2 = 0; j2 < 8; ++j2) {
            total += fin[j2] / fmaxf(fin[8 + j2], 1.f);
        }
        out[0] = total * (1.f / 8.f);
    }
}

extern "C" void kernel_launch(void* const* d_in, const int* in_sizes, int n_in,
                              void* d_out, int out_size, void* d_ws, size_t ws_size,
                              hipStream_t stream)
{
    const float* pred = (const float*)d_in[0];  // [32,2,256,1216] f32
    const float* gt   = (const float*)d_in[1];  // [32,1,256,1216] f32
    const int*   wm   = (const int*)d_in[2];    // [32,1,256,1216] i32
    float* part = (float*)d_ws;                 // GRID*16 floats = 64 KB

    // No memset needed: every part[] slot is written by the main kernel.
    seg_mse_kernel<<<GRID, BLOCKSZ, 0, stream>>>(pred, gt, wm, part);
    finalize_kernel<<<1, 1024, 0, stream>>>(part, (float*)d_out);
}